// Round 1
// baseline (16798.196 us; speedup 1.0000x reference)
//
#include <hip/hip_runtime.h>
#include <math.h>

#define B_ 4
#define D_ 768
#define NH_ 12
#define HD_ 64
#define FF_ 3072
#define L_ 256
#define PD_ 768
#define GRID_ 16
#define P_ 16
#define IMG_ 256
#define M_ (B_*L_)          // 1024 rows
#define NCONV_ (B_*128*IMG_*IMG_)  // 33554432

__device__ __forceinline__ float mishf(float x){
    float sp = (x > 20.f) ? x : log1pf(expf(x));
    return x * tanhf(sp);
}

__device__ __forceinline__ int refl(int i, int n){
    if (i < 0) i = -i;
    if (i >= n) i = 2*n - 2 - i;
    return i;
}

// ---------------- patchify: x[B,3,256,256] -> t[B,L,PD]
__global__ __launch_bounds__(256) void k_patchify(const float* __restrict__ x, float* __restrict__ t){
    int idx = blockIdx.x*256 + threadIdx.x;         // B*L*PD
    int d = idx % PD_; int l = (idx/PD_) % L_; int b = idx/(PD_*L_);
    int c = d % 3; int p = d / 3; int p1 = p / P_; int p2 = p % P_;
    int gh = l / GRID_; int gw = l % GRID_;
    int sy = gh*P_ + p1, sx = gw*P_ + p2;
    t[idx] = x[(((size_t)b*3 + c)*IMG_ + sy)*IMG_ + sx];
}

// ---------------- RMSNorm (row length D); optional per-(l,d) additive vector (pos embed)
__global__ __launch_bounds__(256) void k_rms(const float* __restrict__ x, const float* __restrict__ w,
                                             const float* __restrict__ addv, float* __restrict__ y){
    int row = blockIdx.x;
    const float* xr = x + (size_t)row * D_;
    float s = 0.f;
    for (int i = threadIdx.x; i < D_; i += 256){ float v = xr[i]; s += v*v; }
    __shared__ float red[256];
    red[threadIdx.x] = s; __syncthreads();
    for (int o = 128; o > 0; o >>= 1){
        if (threadIdx.x < o) red[threadIdx.x] += red[threadIdx.x+o];
        __syncthreads();
    }
    float rstd = rsqrtf(red[0]/(float)D_ + 1e-5f);
    int l = row % L_;
    for (int i = threadIdx.x; i < D_; i += 256){
        float v = xr[i]*rstd*w[i];
        if (addv) v += addv[(size_t)l*D_ + i];
        y[(size_t)row*D_ + i] = v;
    }
}

// ---------------- fp32 tiled GEMM: C[M,N] = A[M,K] @ W[K,N] (+bias) (+res)
#define BM 64
#define BN 64
#define BK 16
__global__ __launch_bounds__(256) void k_gemm(const float* __restrict__ A, const float* __restrict__ W,
                                              float* __restrict__ C, const float* __restrict__ bias,
                                              const float* __restrict__ res, int N, int K){
    __shared__ float As[BK][BM+1];
    __shared__ float Ws[BK][BN+1];
    int tid = threadIdx.x;
    int tx = tid & 15, ty = tid >> 4;
    int bx = blockIdx.x, by = blockIdx.y;
    float acc[4][4] = {};
    for (int kt = 0; kt < K; kt += BK){
        #pragma unroll
        for (int i = 0; i < 4; ++i){
            int e = i*256 + tid;
            int ml = e >> 4, kk = e & 15;
            As[kk][ml] = A[(size_t)(by*BM + ml)*K + kt + kk];
            int kk2 = e >> 6, nl = e & 63;
            Ws[kk2][nl] = W[(size_t)(kt + kk2)*N + bx*BN + nl];
        }
        __syncthreads();
        #pragma unroll
        for (int kk = 0; kk < BK; ++kk){
            float a[4], b[4];
            #pragma unroll
            for (int j = 0; j < 4; ++j){ a[j] = As[kk][ty*4+j]; b[j] = Ws[kk][tx*4+j]; }
            #pragma unroll
            for (int ii = 0; ii < 4; ++ii)
                #pragma unroll
                for (int jj = 0; jj < 4; ++jj)
                    acc[ii][jj] += a[ii]*b[jj];
        }
        __syncthreads();
    }
    #pragma unroll
    for (int ii = 0; ii < 4; ++ii){
        int m = by*BM + ty*4 + ii;
        #pragma unroll
        for (int jj = 0; jj < 4; ++jj){
            int n = bx*BN + tx*4 + jj;
            float v = acc[ii][jj];
            if (bias) v += bias[n];
            size_t o = (size_t)m*N + n;
            if (res) v += res[o];
            C[o] = v;
        }
    }
}

// ---------------- attention: one block per (b, h, q-row). qkv layout [B,L,3D].
__global__ __launch_bounds__(256) void k_attn(const float* __restrict__ qkv, float* __restrict__ out){
    int bid = blockIdx.x;                 // B*NH*L
    int q = bid % L_; int h = (bid / L_) % NH_; int b = bid / (L_*NH_);
    const float* base = qkv + (size_t)b * L_ * 3 * D_;
    __shared__ float qs[HD_];
    __shared__ float wgt[L_];
    __shared__ float red[256];
    int tid = threadIdx.x;
    if (tid < HD_) qs[tid] = base[(size_t)q*3*D_ + h*HD_ + tid];
    __syncthreads();
    const float* kr = base + (size_t)tid*3*D_ + D_ + h*HD_;
    float dot = 0.f;
    #pragma unroll
    for (int d = 0; d < HD_; ++d) dot += qs[d]*kr[d];
    dot *= (1.0f/64.0f);   // s applied to both q and k: 1/sqrt(HD)^2
    red[tid] = dot; __syncthreads();
    for (int o = 128; o > 0; o >>= 1){
        if (tid < o) red[tid] = fmaxf(red[tid], red[tid+o]);
        __syncthreads();
    }
    float mx = red[0]; __syncthreads();
    float e = expf(dot - mx);
    wgt[tid] = e;
    red[tid] = e; __syncthreads();
    for (int o = 128; o > 0; o >>= 1){
        if (tid < o) red[tid] += red[tid+o];
        __syncthreads();
    }
    float inv = 1.0f/red[0];
    if (tid < HD_){
        float o = 0.f;
        const float* vbase = base + 2*D_ + h*HD_ + tid;
        for (int k = 0; k < L_; ++k) o += wgt[k] * vbase[(size_t)k*3*D_];
        out[((size_t)b*L_ + q)*D_ + h*HD_ + tid] = o * inv;
    }
}

// ---------------- GLU + mish: g[r,j] = mish(h[r,j]) * h[r,j+FF]
__global__ __launch_bounds__(256) void k_glu(const float* __restrict__ hf, float* __restrict__ g){
    int idx = blockIdx.x*256 + threadIdx.x;        // M_*FF
    int j = idx % FF_; int r = idx / FF_;
    const float* row = hf + (size_t)r*2*FF_;
    g[idx] = mishf(row[j]) * row[j+FF_];
}

// ---------------- unpatchify: t[B,L,PD] -> img[B,3,256,256]
__global__ __launch_bounds__(256) void k_unpatchify(const float* __restrict__ t, float* __restrict__ img){
    int idx = blockIdx.x*256 + threadIdx.x;        // B*3*IMG*IMG
    int sx = idx % IMG_; int sy = (idx/IMG_)%IMG_; int c = (idx/(IMG_*IMG_))%3; int b = idx/(3*IMG_*IMG_);
    int gh = sy / P_, p1 = sy % P_, gw = sx / P_, p2 = sx % P_;
    img[idx] = t[(((size_t)b*L_) + gh*GRID_+gw)*PD_ + (p1*P_+p2)*3 + c];
}

// ---------------- conv_in: 3->128, 3x3, reflect pad 1
__global__ __launch_bounds__(256) void k_conv_in(const float* __restrict__ img, const float* __restrict__ w,
                                                 float* __restrict__ out){
    int idx = blockIdx.x*256 + threadIdx.x;        // B*128*IMG*IMG
    int x = idx % IMG_; int y = (idx/IMG_)%IMG_; int oc = (idx/(IMG_*IMG_))%128; int b = idx/(128*IMG_*IMG_);
    float acc = 0.f;
    #pragma unroll
    for (int ic = 0; ic < 3; ++ic){
        const float* ip = img + ((size_t)(b*3+ic))*IMG_*IMG_;
        #pragma unroll
        for (int kh = 0; kh < 3; ++kh){
            int sy = refl(y-1+kh, IMG_);
            #pragma unroll
            for (int kw = 0; kw < 3; ++kw){
                int sx = refl(x-1+kw, IMG_);
                acc += ip[sy*IMG_+sx] * w[((oc*3+ic)*3+kh)*3+kw];
            }
        }
    }
    out[idx] = acc;
}

// ---------------- depthwise 5x5 conv, reflect pad, dilation
__global__ __launch_bounds__(256) void k_dwconv(const float* __restrict__ in, const float* __restrict__ w,
                                                float* __restrict__ out, int pad, int dil){
    int idx = blockIdx.x*256 + threadIdx.x;        // B*128*IMG*IMG
    int x = idx % IMG_; int y = (idx/IMG_)%IMG_; int c = (idx/(IMG_*IMG_))%128; int b = idx/(128*IMG_*IMG_);
    const float* ip = in + ((size_t)(b*128+c))*IMG_*IMG_;
    const float* wc = w + c*25;
    float acc = 0.f;
    #pragma unroll
    for (int kh = 0; kh < 5; ++kh){
        int sy = refl(y - pad + kh*dil, IMG_);
        #pragma unroll
        for (int kw = 0; kw < 5; ++kw){
            int sx = refl(x - pad + kw*dil, IMG_);
            acc += ip[sy*IMG_+sx] * wc[kh*5+kw];
        }
    }
    out[idx] = acc;
}

// ---------------- group norm stats: grid = B*8 groups, 16 ch each
__global__ __launch_bounds__(256) void k_gn_stats(const float* __restrict__ x, float* __restrict__ stats){
    int bg = blockIdx.x; int b = bg >> 3, g = bg & 7;
    const float* p = x + ((size_t)b*128 + g*16)*IMG_*IMG_;
    const int n = 16*IMG_*IMG_;
    float s = 0.f, sq = 0.f;
    for (int i = threadIdx.x; i < n; i += 256){ float v = p[i]; s += v; sq += v*v; }
    __shared__ float r1[256], r2[256];
    r1[threadIdx.x] = s; r2[threadIdx.x] = sq; __syncthreads();
    for (int o = 128; o > 0; o >>= 1){
        if (threadIdx.x < o){ r1[threadIdx.x] += r1[threadIdx.x+o]; r2[threadIdx.x] += r2[threadIdx.x+o]; }
        __syncthreads();
    }
    if (threadIdx.x == 0){
        float m = r1[0]/(float)n;
        float var = r2[0]/(float)n - m*m;
        stats[bg*2]   = m;
        stats[bg*2+1] = rsqrtf(var + 1e-5f);
    }
}

// ---------------- gn normalize + affine + mish (+ optional residual add AFTER mish)
__global__ __launch_bounds__(256) void k_gn_apply(const float* __restrict__ x, const float* __restrict__ stats,
                                                  const float* __restrict__ w, const float* __restrict__ bb,
                                                  const float* __restrict__ res, float* __restrict__ y){
    int idx = blockIdx.x*256 + threadIdx.x;        // B*128*IMG*IMG
    int c = (idx/(IMG_*IMG_)) % 128; int b = idx/(128*IMG_*IMG_);
    int bg = b*8 + (c >> 4);
    float m = stats[bg*2], rs = stats[bg*2+1];
    float v = (x[idx]-m)*rs*w[c] + bb[c];
    v = mishf(v);
    if (res) v += res[idx];
    y[idx] = v;
}

// ---------------- head conv: 128->1, 3x3, reflect pad 1
__global__ __launch_bounds__(256) void k_head(const float* __restrict__ in, const float* __restrict__ w,
                                              float* __restrict__ out){
    int idx = blockIdx.x*256 + threadIdx.x;        // B*IMG*IMG
    int x = idx % IMG_; int y = (idx/IMG_)%IMG_; int b = idx/(IMG_*IMG_);
    float acc = 0.f;
    for (int c = 0; c < 128; ++c){
        const float* ip = in + ((size_t)(b*128+c))*IMG_*IMG_;
        const float* wc = w + c*9;
        #pragma unroll
        for (int kh = 0; kh < 3; ++kh){
            int sy = refl(y-1+kh, IMG_);
            #pragma unroll
            for (int kw = 0; kw < 3; ++kw){
                int sx = refl(x-1+kw, IMG_);
                acc += ip[sy*IMG_+sx] * wc[kh*3+kw];
            }
        }
    }
    out[idx] = acc;
}

// =======================================================================

static void run_block(const float* an, const float* qw, const float* ow,
                      const float* fn, const float* w1, const float* w2,
                      float* t, float* nbuf, float* qkv, float* att,
                      float* ffh, float* g, hipStream_t stream){
    k_rms<<<M_, 256, 0, stream>>>(t, an, nullptr, nbuf);
    k_gemm<<<dim3(3*D_/BN, M_/BM), 256, 0, stream>>>(nbuf, qw, qkv, nullptr, nullptr, 3*D_, D_);
    k_attn<<<B_*NH_*L_, 256, 0, stream>>>(qkv, att);
    k_gemm<<<dim3(D_/BN, M_/BM), 256, 0, stream>>>(att, ow, t, nullptr, t, D_, D_);
    k_rms<<<M_, 256, 0, stream>>>(t, fn, nullptr, nbuf);
    k_gemm<<<dim3(2*FF_/BN, M_/BM), 256, 0, stream>>>(nbuf, w1, ffh, nullptr, nullptr, 2*FF_, D_);
    k_glu<<<(M_*FF_)/256, 256, 0, stream>>>(ffh, g);
    k_gemm<<<dim3(D_/BN, M_/BM), 256, 0, stream>>>(g, w2, t, nullptr, t, D_, FF_);
}

extern "C" void kernel_launch(void* const* d_in, const int* in_sizes, int n_in,
                              void* d_out, int out_size, void* d_ws, size_t ws_size,
                              hipStream_t stream){
    const float* x              = (const float*)d_in[0];
    const float* pe_norm_w      = (const float*)d_in[1];
    const float* pe_proj_w      = (const float*)d_in[2];
    const float* pe_proj_b      = (const float*)d_in[3];
    const float* pe_norm_out_w  = (const float*)d_in[4];
    const float* pos_embed      = (const float*)d_in[5];
    const float* in_attn_norm_w = (const float*)d_in[6];
    const float* in_qkv_w       = (const float*)d_in[7];
    const float* in_out_w       = (const float*)d_in[8];
    const float* in_ff_norm_w   = (const float*)d_in[9];
    const float* in_w1          = (const float*)d_in[10];
    const float* in_w2          = (const float*)d_in[11];
    const float* mid_attn_norm_w= (const float*)d_in[12];
    const float* mid_qkv_w      = (const float*)d_in[13];
    const float* mid_out_w      = (const float*)d_in[14];
    const float* mid_ff_norm_w  = (const float*)d_in[15];
    const float* mid_w1         = (const float*)d_in[16];
    const float* mid_w2         = (const float*)d_in[17];
    const float* out_skip_w     = (const float*)d_in[18];
    const float* out_skip_b     = (const float*)d_in[19];
    const float* out_attn_norm_w= (const float*)d_in[20];
    const float* out_qkv_w      = (const float*)d_in[21];
    const float* out_out_w      = (const float*)d_in[22];
    const float* out_ff_norm_w  = (const float*)d_in[23];
    const float* out_w1         = (const float*)d_in[24];
    const float* out_w2         = (const float*)d_in[25];
    const float* final_norm_w   = (const float*)d_in[26];
    const float* ol_proj_w      = (const float*)d_in[27];
    const float* ol_proj_b      = (const float*)d_in[28];
    const float* rb_conv_in_w   = (const float*)d_in[29];
    const float* rb_gn_w        = (const float*)d_in[30];
    const float* rb_gn_b        = (const float*)d_in[31];
    const float* rb_conv1_w     = (const float*)d_in[32];
    const float* rb_conv2_w     = (const float*)d_in[33];
    const float* head_conv_w    = (const float*)d_in[34];

    float* ws = (float*)d_ws;
    const size_t TD = (size_t)M_ * D_;          // 786432
    float* t    = ws;
    float* skip = ws + TD;
    float* nbuf = ws + 2*TD;
    float* t2   = ws + 3*TD;
    float* stats= ws + 4*TD;                    // 64 floats
    float* S    = ws + 4*TD + 64;
    float* qkv  = S;                            // M*3D = 2359296
    float* att  = S + (size_t)M_*3*D_;          // 786432
    float* ffh  = S;                            // M*2FF = 6291456
    float* g    = S + (size_t)M_*2*FF_;         // 3145728
    float* ybuf = S;                            // 786432
    float* img  = S + TD;                       // 786432
    float* cA   = S + 2*TD;                     // 33554432
    float* cB   = cA + (size_t)NCONV_;          // 33554432

    // --- patch embed
    k_patchify<<<(B_*L_*PD_)/256, 256, 0, stream>>>(x, t2);
    k_rms<<<M_, 256, 0, stream>>>(t2, pe_norm_w, nullptr, nbuf);
    k_gemm<<<dim3(D_/BN, M_/BM), 256, 0, stream>>>(nbuf, pe_proj_w, t2, pe_proj_b, nullptr, D_, D_);
    k_rms<<<M_, 256, 0, stream>>>(t2, pe_norm_out_w, pos_embed, t);

    // --- 6 in blocks
    for (int i = 0; i < 6; ++i){
        run_block(in_attn_norm_w + (size_t)i*D_,
                  in_qkv_w + (size_t)i*D_*3*D_,
                  in_out_w + (size_t)i*D_*D_,
                  in_ff_norm_w + (size_t)i*D_,
                  in_w1 + (size_t)i*D_*2*FF_,
                  in_w2 + (size_t)i*FF_*D_,
                  t, nbuf, qkv, att, ffh, g, stream);
    }
    hipMemcpyAsync(skip, t, TD*sizeof(float), hipMemcpyDeviceToDevice, stream);

    // --- 3 middle blocks
    for (int i = 0; i < 3; ++i){
        run_block(mid_attn_norm_w + (size_t)i*D_,
                  mid_qkv_w + (size_t)i*D_*3*D_,
                  mid_out_w + (size_t)i*D_*D_,
                  mid_ff_norm_w + (size_t)i*D_,
                  mid_w1 + (size_t)i*D_*2*FF_,
                  mid_w2 + (size_t)i*FF_*D_,
                  t, nbuf, qkv, att, ffh, g, stream);
    }

    // --- skip concat projection: t2 = [t, skip] @ out_skip_w + b
    k_gemm<<<dim3(D_/BN, M_/BM), 256, 0, stream>>>(t, out_skip_w, t2, out_skip_b, nullptr, D_, D_);
    k_gemm<<<dim3(D_/BN, M_/BM), 256, 0, stream>>>(skip, out_skip_w + (size_t)D_*D_, t2, nullptr, t2, D_, D_);

    // --- out block (operates on t2)
    run_block(out_attn_norm_w, out_qkv_w, out_out_w, out_ff_norm_w, out_w1, out_w2,
              t2, nbuf, qkv, att, ffh, g, stream);

    // --- final norm + out proj + unpatchify
    k_rms<<<M_, 256, 0, stream>>>(t2, final_norm_w, nullptr, nbuf);
    k_gemm<<<dim3(PD_/BN, M_/BM), 256, 0, stream>>>(nbuf, ol_proj_w, ybuf, ol_proj_b, nullptr, PD_, D_);
    k_unpatchify<<<(B_*3*IMG_*IMG_)/256, 256, 0, stream>>>(ybuf, img);

    // --- ResNet head
    k_conv_in<<<NCONV_/256, 256, 0, stream>>>(img, rb_conv_in_w, cA);
    k_gn_stats<<<32, 256, 0, stream>>>(cA, stats);
    k_gn_apply<<<NCONV_/256, 256, 0, stream>>>(cA, stats, rb_gn_w, rb_gn_b, nullptr, cB);          // h -> cB
    k_dwconv<<<NCONV_/256, 256, 0, stream>>>(cB, rb_conv1_w, cA, 2, 1);
    k_gn_stats<<<32, 256, 0, stream>>>(cA, stats);
    k_gn_apply<<<NCONV_/256, 256, 0, stream>>>(cA, stats, rb_gn_w+128, rb_gn_b+128, cB, cA);       // h = res + mish(gn(conv))
    k_gn_stats<<<32, 256, 0, stream>>>(cA, stats);
    k_gn_apply<<<NCONV_/256, 256, 0, stream>>>(cA, stats, rb_gn_w+256, rb_gn_b+256, nullptr, cB);  // h -> cB
    k_dwconv<<<NCONV_/256, 256, 0, stream>>>(cB, rb_conv2_w, cA, 6, 3);
    k_gn_stats<<<32, 256, 0, stream>>>(cA, stats);
    k_gn_apply<<<NCONV_/256, 256, 0, stream>>>(cA, stats, rb_gn_w+384, rb_gn_b+384, cB, cA);
    k_gn_stats<<<32, 256, 0, stream>>>(cA, stats);
    k_gn_apply<<<NCONV_/256, 256, 0, stream>>>(cA, stats, rb_gn_w+512, rb_gn_b+512, nullptr, cA);
    k_head<<<(B_*IMG_*IMG_)/256, 256, 0, stream>>>(cA, head_conv_w, (float*)d_out);
}

// Round 2
// 5663.412 us; speedup vs baseline: 2.9661x; 2.9661x over previous
//
#include <hip/hip_runtime.h>
#include <math.h>

#define B_ 4
#define D_ 768
#define NH_ 12
#define HD_ 64
#define FF_ 3072
#define L_ 256
#define PD_ 768
#define GRID_ 16
#define P_ 16
#define IMG_ 256
#define M_ (B_*L_)          // 1024 rows
#define NCONV_ (B_*128*IMG_*IMG_)  // 33554432

typedef __attribute__((ext_vector_type(8))) short short8;
typedef __attribute__((ext_vector_type(4))) float f32x4;

__device__ __forceinline__ float mishf(float x){
    float sp = (x > 20.f) ? x : log1pf(expf(x));
    return x * tanhf(sp);
}

__device__ __forceinline__ int refl(int i, int n){
    if (i < 0) i = -i;
    if (i >= n) i = 2*n - 2 - i;
    return i;
}

__device__ __forceinline__ unsigned short f2bf(float f){
    unsigned int u = __float_as_uint(f);
    unsigned int r = (u + 0x7FFFu + ((u >> 16) & 1u)) >> 16;
    return (unsigned short)r;
}

// ---------------- patchify: x[B,3,256,256] -> t[B,L,PD]
__global__ __launch_bounds__(256) void k_patchify(const float* __restrict__ x, float* __restrict__ t){
    int idx = blockIdx.x*256 + threadIdx.x;         // B*L*PD
    int d = idx % PD_; int l = (idx/PD_) % L_; int b = idx/(PD_*L_);
    int c = d % 3; int p = d / 3; int p1 = p / P_; int p2 = p % P_;
    int gh = l / GRID_; int gw = l % GRID_;
    int sy = gh*P_ + p1, sx = gw*P_ + p2;
    t[idx] = x[(((size_t)b*3 + c)*IMG_ + sy)*IMG_ + sx];
}

// ---------------- RMSNorm (row length D); optional per-(l,d) additive vector (pos embed)
__global__ __launch_bounds__(256) void k_rms(const float* __restrict__ x, const float* __restrict__ w,
                                             const float* __restrict__ addv, float* __restrict__ y){
    int row = blockIdx.x;
    const float* xr = x + (size_t)row * D_;
    float s = 0.f;
    for (int i = threadIdx.x; i < D_; i += 256){ float v = xr[i]; s += v*v; }
    __shared__ float red[256];
    red[threadIdx.x] = s; __syncthreads();
    for (int o = 128; o > 0; o >>= 1){
        if (threadIdx.x < o) red[threadIdx.x] += red[threadIdx.x+o];
        __syncthreads();
    }
    float rstd = rsqrtf(red[0]/(float)D_ + 1e-5f);
    int l = row % L_;
    for (int i = threadIdx.x; i < D_; i += 256){
        float v = xr[i]*rstd*w[i];
        if (addv) v += addv[(size_t)l*D_ + i];
        y[(size_t)row*D_ + i] = v;
    }
}

// ---------------- bf16 MFMA GEMM: C[M,N] = A[M,K] @ W[K,N] (+bias) (+res)
// 64x64 block tile, 4 waves of 32x32. fp32 inputs converted to bf16 in staging.
// A/B fragments use the SAME k-slot convention (lane&15 = row/col,
// lane>>4 selects 8 contiguous k) -> correct under any HW k-permutation.
// C/D layout (m89-verified): col = lane&15, row = (lane>>4)*4 + reg.
__global__ __launch_bounds__(256) void k_gemm(const float* __restrict__ A, const float* __restrict__ W,
                                              float* __restrict__ C, const float* __restrict__ bias,
                                              const float* __restrict__ res, int N, int K){
    __shared__ unsigned short As[64][40];   // [m][k], 80B rows (16B aligned, conflict-light)
    __shared__ unsigned short Ws[64][40];   // [n][k]
    int tid = threadIdx.x;
    int lane = tid & 63, wid = tid >> 6;
    int wr = wid >> 1, wc = wid & 1;        // wave tile origin: (wr*32, wc*32)
    int row0 = blockIdx.y * 64, col0 = blockIdx.x * 64;
    f32x4 acc[2][2];
    #pragma unroll
    for (int i = 0; i < 2; ++i)
        #pragma unroll
        for (int j = 0; j < 2; ++j) acc[i][j] = (f32x4){0.f,0.f,0.f,0.f};

    int lg = lane >> 4;                     // k-group 0..3
    int lr = lane & 15;

    for (int kt = 0; kt < K; kt += 32){
        __syncthreads();
        // stage A: 64 rows x 32 k (fp32 -> bf16); 512 float4 loads / 256 threads
        #pragma unroll
        for (int i = 0; i < 2; ++i){
            int e = i*256 + tid;
            int r = e >> 3, c4 = (e & 7) * 4;
            const float4 v = *(const float4*)(A + (size_t)(row0 + r)*K + kt + c4);
            unsigned short* dst = &As[r][c4];
            dst[0]=f2bf(v.x); dst[1]=f2bf(v.y); dst[2]=f2bf(v.z); dst[3]=f2bf(v.w);
        }
        // stage W transposed: thread handles n = tid&63, k-range (tid>>6)*8 .. +8
        {
            int n = tid & 63, kg = tid >> 6;
            unsigned short tmp[8];
            #pragma unroll
            for (int j = 0; j < 8; ++j)
                tmp[j] = f2bf(W[(size_t)(kt + kg*8 + j)*N + col0 + n]);
            *(short8*)(&Ws[n][kg*8]) = *(short8*)tmp;
        }
        __syncthreads();
        // fragments + MFMA
        short8 a[2], b[2];
        #pragma unroll
        for (int i = 0; i < 2; ++i)
            a[i] = *(const short8*)(&As[wr*32 + i*16 + lr][lg*8]);
        #pragma unroll
        for (int j = 0; j < 2; ++j)
            b[j] = *(const short8*)(&Ws[wc*32 + j*16 + lr][lg*8]);
        #pragma unroll
        for (int i = 0; i < 2; ++i)
            #pragma unroll
            for (int j = 0; j < 2; ++j)
                acc[i][j] = __builtin_amdgcn_mfma_f32_16x16x32_bf16(a[i], b[j], acc[i][j], 0, 0, 0);
    }
    // epilogue
    #pragma unroll
    for (int i = 0; i < 2; ++i){
        #pragma unroll
        for (int j = 0; j < 2; ++j){
            #pragma unroll
            for (int q = 0; q < 4; ++q){
                int m = row0 + wr*32 + i*16 + lg*4 + q;
                int n = col0 + wc*32 + j*16 + lr;
                float v = acc[i][j][q];
                if (bias) v += bias[n];
                size_t o = (size_t)m*N + n;
                if (res) v += res[o];
                C[o] = v;
            }
        }
    }
}

// ---------------- attention: one block per (b, h, q-row). qkv layout [B,L,3D].
__global__ __launch_bounds__(256) void k_attn(const float* __restrict__ qkv, float* __restrict__ out){
    int bid = blockIdx.x;                 // B*NH*L
    int q = bid % L_; int h = (bid / L_) % NH_; int b = bid / (L_*NH_);
    const float* base = qkv + (size_t)b * L_ * 3 * D_;
    __shared__ float qs[HD_];
    __shared__ float wgt[L_];
    __shared__ float red[256];
    __shared__ float po[4][HD_];
    int tid = threadIdx.x;
    if (tid < HD_) qs[tid] = base[(size_t)q*3*D_ + h*HD_ + tid];
    __syncthreads();
    const float* kr = base + (size_t)tid*3*D_ + D_ + h*HD_;
    float dot = 0.f;
    #pragma unroll
    for (int d = 0; d < HD_; ++d) dot += qs[d]*kr[d];
    dot *= (1.0f/64.0f);   // s applied to both q and k: 1/sqrt(HD)^2
    red[tid] = dot; __syncthreads();
    for (int o = 128; o > 0; o >>= 1){
        if (tid < o) red[tid] = fmaxf(red[tid], red[tid+o]);
        __syncthreads();
    }
    float mx = red[0]; __syncthreads();
    float e = expf(dot - mx);
    wgt[tid] = e;
    red[tid] = e; __syncthreads();
    for (int o = 128; o > 0; o >>= 1){
        if (tid < o) red[tid] += red[tid+o];
        __syncthreads();
    }
    float inv = 1.0f/red[0];
    __syncthreads();
    // PV with all 256 threads: 4 k-chunks of 64
    {
        int grp = tid >> 6, ln = tid & 63;
        const float* vbase = base + 2*D_ + h*HD_ + ln;
        float o = 0.f;
        #pragma unroll 4
        for (int k = grp*64; k < grp*64 + 64; ++k) o += wgt[k] * vbase[(size_t)k*3*D_];
        po[grp][ln] = o;
    }
    __syncthreads();
    if (tid < HD_){
        float o = (po[0][tid] + po[1][tid] + po[2][tid] + po[3][tid]) * inv;
        out[((size_t)b*L_ + q)*D_ + h*HD_ + tid] = o;
    }
}

// ---------------- GLU + mish (float4): g[r,j] = mish(h[r,j]) * h[r,j+FF]
__global__ __launch_bounds__(256) void k_glu(const float* __restrict__ hf, float* __restrict__ g){
    int idx4 = blockIdx.x*256 + threadIdx.x;       // (M_*FF)/4
    int e = idx4 * 4;
    int j = e % FF_; int r = e / FF_;
    const float* row = hf + (size_t)r*2*FF_;
    float4 a = *(const float4*)(row + j);
    float4 b = *(const float4*)(row + j + FF_);
    float4 o;
    o.x = mishf(a.x)*b.x; o.y = mishf(a.y)*b.y; o.z = mishf(a.z)*b.z; o.w = mishf(a.w)*b.w;
    *(float4*)(g + e) = o;
}

// ---------------- unpatchify: t[B,L,PD] -> img[B,3,256,256]
__global__ __launch_bounds__(256) void k_unpatchify(const float* __restrict__ t, float* __restrict__ img){
    int idx = blockIdx.x*256 + threadIdx.x;        // B*3*IMG*IMG
    int sx = idx % IMG_; int sy = (idx/IMG_)%IMG_; int c = (idx/(IMG_*IMG_))%3; int b = idx/(3*IMG_*IMG_);
    int gh = sy / P_, p1 = sy % P_, gw = sx / P_, p2 = sx % P_;
    img[idx] = t[(((size_t)b*L_) + gh*GRID_+gw)*PD_ + (p1*P_+p2)*3 + c];
}

// ---------------- conv_in: 3->128, 3x3, reflect pad 1
__global__ __launch_bounds__(256) void k_conv_in(const float* __restrict__ img, const float* __restrict__ w,
                                                 float* __restrict__ out){
    int idx = blockIdx.x*256 + threadIdx.x;        // B*128*IMG*IMG
    int x = idx % IMG_; int y = (idx/IMG_)%IMG_; int oc = (idx/(IMG_*IMG_))%128; int b = idx/(128*IMG_*IMG_);
    float acc = 0.f;
    #pragma unroll
    for (int ic = 0; ic < 3; ++ic){
        const float* ip = img + ((size_t)(b*3+ic))*IMG_*IMG_;
        #pragma unroll
        for (int kh = 0; kh < 3; ++kh){
            int sy = refl(y-1+kh, IMG_);
            #pragma unroll
            for (int kw = 0; kw < 3; ++kw){
                int sx = refl(x-1+kw, IMG_);
                acc += ip[sy*IMG_+sx] * w[((oc*3+ic)*3+kh)*3+kw];
            }
        }
    }
    out[idx] = acc;
}

// ---------------- depthwise 5x5 conv, reflect pad, dilation
__global__ __launch_bounds__(256) void k_dwconv(const float* __restrict__ in, const float* __restrict__ w,
                                                float* __restrict__ out, int pad, int dil){
    int idx = blockIdx.x*256 + threadIdx.x;        // B*128*IMG*IMG
    int x = idx % IMG_; int y = (idx/IMG_)%IMG_; int c = (idx/(IMG_*IMG_))%128; int b = idx/(128*IMG_*IMG_);
    const float* ip = in + ((size_t)(b*128+c))*IMG_*IMG_;
    const float* wc = w + c*25;
    float acc = 0.f;
    #pragma unroll
    for (int kh = 0; kh < 5; ++kh){
        int sy = refl(y - pad + kh*dil, IMG_);
        #pragma unroll
        for (int kw = 0; kw < 5; ++kw){
            int sx = refl(x - pad + kw*dil, IMG_);
            acc += ip[sy*IMG_+sx] * wc[kh*5+kw];
        }
    }
    out[idx] = acc;
}

// ---------------- group norm stats, two-stage
// stage 1: 32 groups x 64 chunks; each block reduces 16384 elems (4096 float4)
__global__ __launch_bounds__(256) void k_gn_part(const float* __restrict__ x, float* __restrict__ part){
    int bg = blockIdx.x >> 6, ch = blockIdx.x & 63;
    const float4* p4 = (const float4*)(x + (size_t)bg*16*IMG_*IMG_ + (size_t)ch*16384);
    float s = 0.f, sq = 0.f;
    int tid = threadIdx.x;
    #pragma unroll 4
    for (int i = tid; i < 4096; i += 256){
        float4 v = p4[i];
        s  += v.x + v.y + v.z + v.w;
        sq += v.x*v.x + v.y*v.y + v.z*v.z + v.w*v.w;
    }
    #pragma unroll
    for (int o = 32; o > 0; o >>= 1){ s += __shfl_down(s, o); sq += __shfl_down(sq, o); }
    __shared__ float r1[4], r2[4];
    if ((tid & 63) == 0){ r1[tid>>6] = s; r2[tid>>6] = sq; }
    __syncthreads();
    if (tid == 0){
        part[blockIdx.x*2]   = r1[0]+r1[1]+r1[2]+r1[3];
        part[blockIdx.x*2+1] = r2[0]+r2[1]+r2[2]+r2[3];
    }
}
// stage 2: 32 blocks x 64 threads -> stats (mean, rstd per group)
__global__ __launch_bounds__(64) void k_gn_finish(const float* __restrict__ part, float* __restrict__ stats){
    int bg = blockIdx.x, t = threadIdx.x;
    float s  = part[(bg*64 + t)*2];
    float sq = part[(bg*64 + t)*2 + 1];
    #pragma unroll
    for (int o = 32; o > 0; o >>= 1){ s += __shfl_down(s, o); sq += __shfl_down(sq, o); }
    if (t == 0){
        const float n = 16.f*IMG_*IMG_;
        float m = s/n;
        float var = sq/n - m*m;
        stats[bg*2]   = m;
        stats[bg*2+1] = rsqrtf(var + 1e-5f);
    }
}

// ---------------- gn normalize + affine + mish (+ optional residual add AFTER mish), float4
__global__ __launch_bounds__(256) void k_gn_apply(const float* __restrict__ x, const float* __restrict__ stats,
                                                  const float* __restrict__ w, const float* __restrict__ bb,
                                                  const float* __restrict__ res, float* __restrict__ y){
    int idx4 = blockIdx.x*256 + threadIdx.x;       // NCONV/4
    int e = idx4 * 4;
    int c = (e/(IMG_*IMG_)) % 128; int b = e/(128*IMG_*IMG_);
    int bg = b*8 + (c >> 4);
    float m = stats[bg*2], rs = stats[bg*2+1];
    float sc = rs*w[c], sb = bb[c] - m*sc;
    float4 v = *(const float4*)(x + e);
    v.x = mishf(v.x*sc + sb); v.y = mishf(v.y*sc + sb);
    v.z = mishf(v.z*sc + sb); v.w = mishf(v.w*sc + sb);
    if (res){
        float4 r = *(const float4*)(res + e);
        v.x += r.x; v.y += r.y; v.z += r.z; v.w += r.w;
    }
    *(float4*)(y + e) = v;
}

// ---------------- head conv: 128->1, 3x3, reflect pad 1
__global__ __launch_bounds__(256) void k_head(const float* __restrict__ in, const float* __restrict__ w,
                                              float* __restrict__ out){
    int idx = blockIdx.x*256 + threadIdx.x;        // B*IMG*IMG
    int x = idx % IMG_; int y = (idx/IMG_)%IMG_; int b = idx/(IMG_*IMG_);
    float acc = 0.f;
    for (int c = 0; c < 128; ++c){
        const float* ip = in + ((size_t)(b*128+c))*IMG_*IMG_;
        const float* wc = w + c*9;
        #pragma unroll
        for (int kh = 0; kh < 3; ++kh){
            int sy = refl(y-1+kh, IMG_);
            #pragma unroll
            for (int kw = 0; kw < 3; ++kw){
                int sx = refl(x-1+kw, IMG_);
                acc += ip[sy*IMG_+sx] * wc[kh*3+kw];
            }
        }
    }
    out[idx] = acc;
}

// =======================================================================

static void run_block(const float* an, const float* qw, const float* ow,
                      const float* fn, const float* w1, const float* w2,
                      float* t, float* nbuf, float* qkv, float* att,
                      float* ffh, float* g, hipStream_t stream){
    k_rms<<<M_, 256, 0, stream>>>(t, an, nullptr, nbuf);
    k_gemm<<<dim3(3*D_/64, M_/64), 256, 0, stream>>>(nbuf, qw, qkv, nullptr, nullptr, 3*D_, D_);
    k_attn<<<B_*NH_*L_, 256, 0, stream>>>(qkv, att);
    k_gemm<<<dim3(D_/64, M_/64), 256, 0, stream>>>(att, ow, t, nullptr, t, D_, D_);
    k_rms<<<M_, 256, 0, stream>>>(t, fn, nullptr, nbuf);
    k_gemm<<<dim3(2*FF_/64, M_/64), 256, 0, stream>>>(nbuf, w1, ffh, nullptr, nullptr, 2*FF_, D_);
    k_glu<<<(M_*FF_)/1024, 256, 0, stream>>>(ffh, g);
    k_gemm<<<dim3(D_/64, M_/64), 256, 0, stream>>>(g, w2, t, nullptr, t, D_, FF_);
}

extern "C" void kernel_launch(void* const* d_in, const int* in_sizes, int n_in,
                              void* d_out, int out_size, void* d_ws, size_t ws_size,
                              hipStream_t stream){
    const float* x              = (const float*)d_in[0];
    const float* pe_norm_w      = (const float*)d_in[1];
    const float* pe_proj_w      = (const float*)d_in[2];
    const float* pe_proj_b      = (const float*)d_in[3];
    const float* pe_norm_out_w  = (const float*)d_in[4];
    const float* pos_embed      = (const float*)d_in[5];
    const float* in_attn_norm_w = (const float*)d_in[6];
    const float* in_qkv_w       = (const float*)d_in[7];
    const float* in_out_w       = (const float*)d_in[8];
    const float* in_ff_norm_w   = (const float*)d_in[9];
    const float* in_w1          = (const float*)d_in[10];
    const float* in_w2          = (const float*)d_in[11];
    const float* mid_attn_norm_w= (const float*)d_in[12];
    const float* mid_qkv_w      = (const float*)d_in[13];
    const float* mid_out_w      = (const float*)d_in[14];
    const float* mid_ff_norm_w  = (const float*)d_in[15];
    const float* mid_w1         = (const float*)d_in[16];
    const float* mid_w2         = (const float*)d_in[17];
    const float* out_skip_w     = (const float*)d_in[18];
    const float* out_skip_b     = (const float*)d_in[19];
    const float* out_attn_norm_w= (const float*)d_in[20];
    const float* out_qkv_w      = (const float*)d_in[21];
    const float* out_out_w      = (const float*)d_in[22];
    const float* out_ff_norm_w  = (const float*)d_in[23];
    const float* out_w1         = (const float*)d_in[24];
    const float* out_w2         = (const float*)d_in[25];
    const float* final_norm_w   = (const float*)d_in[26];
    const float* ol_proj_w      = (const float*)d_in[27];
    const float* ol_proj_b      = (const float*)d_in[28];
    const float* rb_conv_in_w   = (const float*)d_in[29];
    const float* rb_gn_w        = (const float*)d_in[30];
    const float* rb_gn_b        = (const float*)d_in[31];
    const float* rb_conv1_w     = (const float*)d_in[32];
    const float* rb_conv2_w     = (const float*)d_in[33];
    const float* head_conv_w    = (const float*)d_in[34];

    float* ws = (float*)d_ws;
    const size_t TD = (size_t)M_ * D_;          // 786432
    float* t    = ws;
    float* skip = ws + TD;
    float* nbuf = ws + 2*TD;
    float* t2   = ws + 3*TD;
    float* stats= ws + 4*TD;                    // 64 floats
    float* part = ws + 4*TD + 64;               // 4096 floats
    float* S    = ws + 4*TD + 64 + 4096;
    float* qkv  = S;                            // M*3D = 2359296
    float* att  = S + (size_t)M_*3*D_;          // 786432
    float* ffh  = S;                            // M*2FF = 6291456
    float* g    = S + (size_t)M_*2*FF_;         // 3145728
    float* ybuf = S;                            // 786432
    float* img  = S + TD;                       // 786432
    float* cA   = S + 2*TD;                     // 33554432
    float* cB   = cA + (size_t)NCONV_;          // 33554432

    // --- patch embed
    k_patchify<<<(B_*L_*PD_)/256, 256, 0, stream>>>(x, t2);
    k_rms<<<M_, 256, 0, stream>>>(t2, pe_norm_w, nullptr, nbuf);
    k_gemm<<<dim3(D_/64, M_/64), 256, 0, stream>>>(nbuf, pe_proj_w, t2, pe_proj_b, nullptr, D_, D_);
    k_rms<<<M_, 256, 0, stream>>>(t2, pe_norm_out_w, pos_embed, t);

    // --- 6 in blocks
    for (int i = 0; i < 6; ++i){
        run_block(in_attn_norm_w + (size_t)i*D_,
                  in_qkv_w + (size_t)i*D_*3*D_,
                  in_out_w + (size_t)i*D_*D_,
                  in_ff_norm_w + (size_t)i*D_,
                  in_w1 + (size_t)i*D_*2*FF_,
                  in_w2 + (size_t)i*FF_*D_,
                  t, nbuf, qkv, att, ffh, g, stream);
    }
    hipMemcpyAsync(skip, t, TD*sizeof(float), hipMemcpyDeviceToDevice, stream);

    // --- 3 middle blocks
    for (int i = 0; i < 3; ++i){
        run_block(mid_attn_norm_w + (size_t)i*D_,
                  mid_qkv_w + (size_t)i*D_*3*D_,
                  mid_out_w + (size_t)i*D_*D_,
                  mid_ff_norm_w + (size_t)i*D_,
                  mid_w1 + (size_t)i*D_*2*FF_,
                  mid_w2 + (size_t)i*FF_*D_,
                  t, nbuf, qkv, att, ffh, g, stream);
    }

    // --- skip concat projection: t2 = [t, skip] @ out_skip_w + b
    k_gemm<<<dim3(D_/64, M_/64), 256, 0, stream>>>(t, out_skip_w, t2, out_skip_b, nullptr, D_, D_);
    k_gemm<<<dim3(D_/64, M_/64), 256, 0, stream>>>(skip, out_skip_w + (size_t)D_*D_, t2, nullptr, t2, D_, D_);

    // --- out block (operates on t2)
    run_block(out_attn_norm_w, out_qkv_w, out_out_w, out_ff_norm_w, out_w1, out_w2,
              t2, nbuf, qkv, att, ffh, g, stream);

    // --- final norm + out proj + unpatchify
    k_rms<<<M_, 256, 0, stream>>>(t2, final_norm_w, nullptr, nbuf);
    k_gemm<<<dim3(PD_/64, M_/64), 256, 0, stream>>>(nbuf, ol_proj_w, ybuf, ol_proj_b, nullptr, PD_, D_);
    k_unpatchify<<<(B_*3*IMG_*IMG_)/256, 256, 0, stream>>>(ybuf, img);

    // --- ResNet head
    k_conv_in<<<NCONV_/256, 256, 0, stream>>>(img, rb_conv_in_w, cA);
    k_gn_part<<<2048, 256, 0, stream>>>(cA, part);
    k_gn_finish<<<32, 64, 0, stream>>>(part, stats);
    k_gn_apply<<<NCONV_/1024, 256, 0, stream>>>(cA, stats, rb_gn_w, rb_gn_b, nullptr, cB);          // h -> cB
    k_dwconv<<<NCONV_/256, 256, 0, stream>>>(cB, rb_conv1_w, cA, 2, 1);
    k_gn_part<<<2048, 256, 0, stream>>>(cA, part);
    k_gn_finish<<<32, 64, 0, stream>>>(part, stats);
    k_gn_apply<<<NCONV_/1024, 256, 0, stream>>>(cA, stats, rb_gn_w+128, rb_gn_b+128, cB, cA);       // h = res + mish(gn(conv))
    k_gn_part<<<2048, 256, 0, stream>>>(cA, part);
    k_gn_finish<<<32, 64, 0, stream>>>(part, stats);
    k_gn_apply<<<NCONV_/1024, 256, 0, stream>>>(cA, stats, rb_gn_w+256, rb_gn_b+256, nullptr, cB);  // h -> cB
    k_dwconv<<<NCONV_/256, 256, 0, stream>>>(cB, rb_conv2_w, cA, 6, 3);
    k_gn_part<<<2048, 256, 0, stream>>>(cA, part);
    k_gn_finish<<<32, 64, 0, stream>>>(part, stats);
    k_gn_apply<<<NCONV_/1024, 256, 0, stream>>>(cA, stats, rb_gn_w+384, rb_gn_b+384, cB, cA);
    k_gn_part<<<2048, 256, 0, stream>>>(cA, part);
    k_gn_finish<<<32, 64, 0, stream>>>(part, stats);
    k_gn_apply<<<NCONV_/1024, 256, 0, stream>>>(cA, stats, rb_gn_w+512, rb_gn_b+512, nullptr, cA);
    k_head<<<(B_*IMG_*IMG_)/256, 256, 0, stream>>>(cA, head_conv_w, (float*)d_out);
}

// Round 3
// 3419.695 us; speedup vs baseline: 4.9122x; 1.6561x over previous
//
#include <hip/hip_runtime.h>
#include <math.h>

#define B_ 4
#define D_ 768
#define NH_ 12
#define HD_ 64
#define FF_ 3072
#define L_ 256
#define PD_ 768
#define GRID_ 16
#define P_ 16
#define IMG_ 256
#define M_ (B_*L_)                 // 1024 rows
#define NCONV_ (B_*128*IMG_*IMG_)  // 33554432

typedef __attribute__((ext_vector_type(8))) short short8;
typedef __attribute__((ext_vector_type(4))) float f32x4;
typedef __attribute__((ext_vector_type(4))) unsigned short us4;
typedef __attribute__((ext_vector_type(8))) unsigned short us8;
typedef unsigned short ushort_t;

__device__ __forceinline__ float mishf(float x){
    // mish(x) = x * tanh(log1p(exp(x))) == x * (1 - 2/((1+e^x)^2 + 1))  (exact identity)
    float e = __expf(x);
    float u = (1.f + e) * (1.f + e);
    return x * (1.f - 2.f / (u + 1.f));
}

__device__ __forceinline__ int refl(int i, int n){
    if (i < 0) i = -i;
    if (i >= n) i = 2*n - 2 - i;
    return i;
}

__device__ __forceinline__ ushort_t f2bf(float f){
    unsigned int u = __float_as_uint(f);
    unsigned int r = (u + 0x7FFFu + ((u >> 16) & 1u)) >> 16;
    return (ushort_t)r;
}
__device__ __forceinline__ float bf2f(ushort_t u){
    return __uint_as_float(((unsigned int)u) << 16);
}

// block-wide (256 thr) sum of (s,q); returns valid on tid==0
__device__ __forceinline__ void block_red2(float& s, float& q){
    #pragma unroll
    for (int o = 32; o > 0; o >>= 1){ s += __shfl_down(s, o); q += __shfl_down(q, o); }
    __shared__ float r1[4], r2[4];
    int tid = threadIdx.x;
    if ((tid & 63) == 0){ r1[tid>>6] = s; r2[tid>>6] = q; }
    __syncthreads();
    if (tid == 0){ s = r1[0]+r1[1]+r1[2]+r1[3]; q = r2[0]+r2[1]+r2[2]+r2[3]; }
}

// ---------------- patchify: x[B,3,256,256] -> t[B,L,PD] (f32)
__global__ __launch_bounds__(256) void k_patchify(const float* __restrict__ x, float* __restrict__ t){
    int idx = blockIdx.x*256 + threadIdx.x;
    int d = idx % PD_; int l = (idx/PD_) % L_; int b = idx/(PD_*L_);
    int c = d % 3; int p = d / 3; int p1 = p / P_; int p2 = p % P_;
    int gh = l / GRID_; int gw = l % GRID_;
    int sy = gh*P_ + p1, sx = gw*P_ + p2;
    t[idx] = x[(((size_t)b*3 + c)*IMG_ + sy)*IMG_ + sx];
}

// ---------------- weight transpose+convert: W[K][N] f32 -> Wt[N][K] bf16
__global__ __launch_bounds__(256) void k_wt(const float* __restrict__ b0, const float* __restrict__ b1,
                                            const float* __restrict__ b2, int n0, int n1,
                                            ushort_t* __restrict__ dst, int K, int N){
    int z = blockIdx.z;
    size_t sz = (size_t)K * N;
    const float* src = (z < n0) ? b0 + (size_t)z*sz
                     : (z < n0+n1) ? b1 + (size_t)(z-n0)*sz
                     : b2 + (size_t)(z-n0-n1)*sz;
    ushort_t* out = dst + (size_t)z*sz;
    __shared__ float ld[32][33];
    int k0 = blockIdx.y*32, nc0 = blockIdx.x*32;
    int tid = threadIdx.x;
    int c = tid & 31, r8 = tid >> 5;
    #pragma unroll
    for (int i = 0; i < 4; ++i){
        int k = r8 + i*8;
        ld[k][c] = src[(size_t)(k0+k)*N + nc0 + c];
    }
    __syncthreads();
    #pragma unroll
    for (int i = 0; i < 4; ++i){
        int n = r8 + i*8;
        out[(size_t)(nc0+n)*K + k0 + c] = f2bf(ld[c][n]);
    }
}

// ---------------- RMSNorm; OUT_BF: write bf16 (GEMM input); else f32 (+pos embed add)
template<bool OUT_BF>
__global__ __launch_bounds__(256) void k_rms(const float* __restrict__ x, const float* __restrict__ w,
                                             const float* __restrict__ addv, void* __restrict__ yv){
    int row = blockIdx.x;
    const float* xr = x + (size_t)row * D_;
    float s = 0.f;
    for (int i = threadIdx.x; i < D_; i += 256){ float v = xr[i]; s += v*v; }
    __shared__ float red[256];
    red[threadIdx.x] = s; __syncthreads();
    for (int o = 128; o > 0; o >>= 1){
        if (threadIdx.x < o) red[threadIdx.x] += red[threadIdx.x+o];
        __syncthreads();
    }
    float rstd = rsqrtf(red[0]/(float)D_ + 1e-5f);
    int l = row % L_;
    for (int i = threadIdx.x; i < D_; i += 256){
        float v = xr[i]*rstd*w[i];
        if (addv) v += addv[(size_t)l*D_ + i];
        if (OUT_BF) ((ushort_t*)yv)[(size_t)row*D_ + i] = f2bf(v);
        else        ((float*)yv)[(size_t)row*D_ + i] = v;
    }
}

// ---------------- bf16 MFMA GEMM: C[M,N] = A[M,K](bf16) @ Wt[N,K](bf16) (+bias)(+res), C f32
__global__ __launch_bounds__(256) void k_gemm(const ushort_t* __restrict__ A, const ushort_t* __restrict__ Wt,
                                              float* __restrict__ C, const float* __restrict__ bias,
                                              const float* __restrict__ res, int N, int K){
    __shared__ ushort_t As[64][40];
    __shared__ ushort_t Ws[64][40];
    int tid = threadIdx.x;
    int lane = tid & 63, wid = tid >> 6;
    int wr = wid >> 1, wc = wid & 1;
    int row0 = blockIdx.y * 64, col0 = blockIdx.x * 64;
    f32x4 acc[2][2];
    #pragma unroll
    for (int i = 0; i < 2; ++i)
        #pragma unroll
        for (int j = 0; j < 2; ++j) acc[i][j] = (f32x4){0.f,0.f,0.f,0.f};

    int lg = lane >> 4;
    int lr = lane & 15;
    int sr = tid >> 2, sk = (tid & 3) * 8;

    for (int kt = 0; kt < K; kt += 32){
        __syncthreads();
        *(short8*)&As[sr][sk] = *(const short8*)(A  + (size_t)(row0 + sr)*K + kt + sk);
        *(short8*)&Ws[sr][sk] = *(const short8*)(Wt + (size_t)(col0 + sr)*K + kt + sk);
        __syncthreads();
        short8 a[2], b[2];
        #pragma unroll
        for (int i = 0; i < 2; ++i)
            a[i] = *(const short8*)(&As[wr*32 + i*16 + lr][lg*8]);
        #pragma unroll
        for (int j = 0; j < 2; ++j)
            b[j] = *(const short8*)(&Ws[wc*32 + j*16 + lr][lg*8]);
        #pragma unroll
        for (int i = 0; i < 2; ++i)
            #pragma unroll
            for (int j = 0; j < 2; ++j)
                acc[i][j] = __builtin_amdgcn_mfma_f32_16x16x32_bf16(a[i], b[j], acc[i][j], 0, 0, 0);
    }
    #pragma unroll
    for (int i = 0; i < 2; ++i){
        #pragma unroll
        for (int j = 0; j < 2; ++j){
            #pragma unroll
            for (int q = 0; q < 4; ++q){
                int m = row0 + wr*32 + i*16 + lg*4 + q;
                int n = col0 + wc*32 + j*16 + lr;
                float v = acc[i][j][q];
                if (bias) v += bias[n];
                size_t o = (size_t)m*N + n;
                if (res) v += res[o];
                C[o] = v;
            }
        }
    }
}

// ---------------- attention: one block per (b,h,q). qkv f32 [B,L,3D] -> out bf16 [B,L,D]
__global__ __launch_bounds__(256) void k_attn(const float* __restrict__ qkv, ushort_t* __restrict__ out){
    int bid = blockIdx.x;
    int q = bid % L_; int h = (bid / L_) % NH_; int b = bid / (L_*NH_);
    const float* base = qkv + (size_t)b * L_ * 3 * D_;
    __shared__ float qs[HD_];
    __shared__ float wgt[L_];
    __shared__ float red[256];
    __shared__ float po[4][HD_];
    int tid = threadIdx.x;
    if (tid < HD_) qs[tid] = base[(size_t)q*3*D_ + h*HD_ + tid];
    __syncthreads();
    const float* kr = base + (size_t)tid*3*D_ + D_ + h*HD_;
    float dot = 0.f;
    #pragma unroll
    for (int d = 0; d < HD_; ++d) dot += qs[d]*kr[d];
    dot *= (1.0f/64.0f);
    red[tid] = dot; __syncthreads();
    for (int o = 128; o > 0; o >>= 1){
        if (tid < o) red[tid] = fmaxf(red[tid], red[tid+o]);
        __syncthreads();
    }
    float mx = red[0]; __syncthreads();
    float e = __expf(dot - mx);
    wgt[tid] = e;
    red[tid] = e; __syncthreads();
    for (int o = 128; o > 0; o >>= 1){
        if (tid < o) red[tid] += red[tid+o];
        __syncthreads();
    }
    float inv = 1.0f/red[0];
    __syncthreads();
    {
        int grp = tid >> 6, ln = tid & 63;
        const float* vbase = base + 2*D_ + h*HD_ + ln;
        float o = 0.f;
        #pragma unroll 4
        for (int k = grp*64; k < grp*64 + 64; ++k) o += wgt[k] * vbase[(size_t)k*3*D_];
        po[grp][ln] = o;
    }
    __syncthreads();
    if (tid < HD_){
        float o = (po[0][tid] + po[1][tid] + po[2][tid] + po[3][tid]) * inv;
        out[((size_t)b*L_ + q)*D_ + h*HD_ + tid] = f2bf(o);
    }
}

// ---------------- GLU + mish -> bf16
__global__ __launch_bounds__(256) void k_glu(const float* __restrict__ hf, ushort_t* __restrict__ g){
    int idx4 = blockIdx.x*256 + threadIdx.x;       // (M_*FF)/4
    int e = idx4 * 4;
    int j = e % FF_; int r = e / FF_;
    const float* row = hf + (size_t)r*2*FF_;
    float4 a = *(const float4*)(row + j);
    float4 bb = *(const float4*)(row + j + FF_);
    us4 o;
    o.x = f2bf(mishf(a.x)*bb.x); o.y = f2bf(mishf(a.y)*bb.y);
    o.z = f2bf(mishf(a.z)*bb.z); o.w = f2bf(mishf(a.w)*bb.w);
    *(us4*)(g + e) = o;
}

// ---------------- concat convert: cat[r][0:768]=bf(t), cat[r][768:1536]=bf(skip)
__global__ __launch_bounds__(256) void k_cat(const float* __restrict__ t, const float* __restrict__ skip,
                                             ushort_t* __restrict__ cat){
    int i4 = (blockIdx.x*256 + threadIdx.x) * 4;    // over M*768
    int r = i4 / D_, c = i4 % D_;
    float4 a = *(const float4*)(t + i4);
    float4 b = *(const float4*)(skip + i4);
    us4 ua, ub;
    ua.x=f2bf(a.x); ua.y=f2bf(a.y); ua.z=f2bf(a.z); ua.w=f2bf(a.w);
    ub.x=f2bf(b.x); ub.y=f2bf(b.y); ub.z=f2bf(b.z); ub.w=f2bf(b.w);
    *(us4*)(cat + (size_t)r*1536 + c) = ua;
    *(us4*)(cat + (size_t)r*1536 + 768 + c) = ub;
}

// ---------------- unpatchify: ybuf[B,L,PD] f32 -> img[B,3,256,256] f32
__global__ __launch_bounds__(256) void k_unpatchify(const float* __restrict__ t, float* __restrict__ img){
    int idx = blockIdx.x*256 + threadIdx.x;
    int sx = idx % IMG_; int sy = (idx/IMG_)%IMG_; int c = (idx/(IMG_*IMG_))%3; int b = idx/(3*IMG_*IMG_);
    int gh = sy / P_, p1 = sy % P_, gw = sx / P_, p2 = sx % P_;
    img[idx] = t[(((size_t)b*L_) + gh*GRID_+gw)*PD_ + (p1*P_+p2)*3 + c];
}

// ---------------- conv_in: 3->128, 3x3, reflect; block = (y, oc, b), 256 thr = x row.
// writes bf16 + stats partial (sum, sumsq) per block
__global__ __launch_bounds__(256) void k_conv_in(const float* __restrict__ img, const float* __restrict__ w,
                                                 ushort_t* __restrict__ out, float* __restrict__ partial){
    int y = blockIdx.x, oc = blockIdx.y, b = blockIdx.z;
    int x = threadIdx.x;
    const float* wv = w + oc*27;
    int yy0 = refl(y-1, IMG_), yy2 = refl(y+1, IMG_);
    int xl = (x==0)?1:x-1, xr = (x==255)?254:x+1;
    float acc = 0.f;
    #pragma unroll
    for (int ic = 0; ic < 3; ++ic){
        const float* base = img + ((size_t)(b*3+ic))*IMG_*IMG_;
        const float* r0 = base + (size_t)yy0*IMG_;
        const float* r1 = base + (size_t)y  *IMG_;
        const float* r2 = base + (size_t)yy2*IMG_;
        const float* wk = wv + ic*9;
        acc += r0[xl]*wk[0] + r0[x]*wk[1] + r0[xr]*wk[2];
        acc += r1[xl]*wk[3] + r1[x]*wk[4] + r1[xr]*wk[5];
        acc += r2[xl]*wk[6] + r2[x]*wk[7] + r2[xr]*wk[8];
    }
    out[(((size_t)(b*128+oc))*IMG_ + y)*IMG_ + x] = f2bf(acc);
    float s = acc, q = acc*acc;
    block_red2(s, q);
    if (threadIdx.x == 0){
        int bid = (b*128 + oc)*256 + y;
        partial[bid*2] = s; partial[bid*2+1] = q;
    }
}

// ---------------- stats finish: 32 groups; partial range [bg*nper, bg*nper+nper)
__global__ __launch_bounds__(256) void k_gn_fin(const float* __restrict__ partial, int nper,
                                                float* __restrict__ stats){
    int bg = blockIdx.x, tid = threadIdx.x;
    float s = 0.f, q = 0.f;
    for (int i = tid; i < nper; i += 256){
        s += partial[((size_t)bg*nper + i)*2];
        q += partial[((size_t)bg*nper + i)*2 + 1];
    }
    block_red2(s, q);
    if (tid == 0){
        const float n = 16.f*IMG_*IMG_;
        float m = s/n;
        float var = q/n - m*m;
        stats[bg*2]   = m;
        stats[bg*2+1] = rsqrtf(var + 1e-5f);
    }
}

// ---------------- depthwise 5x5 conv with fused input gn+mish; 32x32 tile.
// in bf16 (raw), st/gw/gb: input's groupnorm; out bf16 raw conv; stats partial of output.
template<int PAD, int DIL>
__global__ __launch_bounds__(256) void k_dw(const ushort_t* __restrict__ in, const float* __restrict__ st,
                                            const float* __restrict__ gw, const float* __restrict__ gb,
                                            const float* __restrict__ cw,
                                            ushort_t* __restrict__ out, float* __restrict__ partial){
    constexpr int S = 32 + 2*PAD;
    __shared__ float tile[S*S];
    int tileid = blockIdx.x, c = blockIdx.y, b = blockIdx.z;
    int x0 = (tileid & 7) * 32, y0 = (tileid >> 3) * 32;
    int tid = threadIdx.x;
    float m  = st[(b*8 + (c>>4))*2];
    float rs = st[(b*8 + (c>>4))*2 + 1];
    float sc = rs * gw[c], sb = gb[c] - m*sc;
    const ushort_t* ip = in + ((size_t)(b*128+c))*IMG_*IMG_;
    for (int i = tid; i < S*S; i += 256){
        int r = i / S, cc = i - r*S;
        int gy = refl(y0 - PAD + r, IMG_);
        int gx = refl(x0 - PAD + cc, IMG_);
        float f = bf2f(ip[(size_t)gy*IMG_ + gx]) * sc + sb;
        tile[i] = mishf(f);
    }
    __syncthreads();
    const float* wc = cw + c*25;
    int tx4 = (tid & 7) * 4, ty = tid >> 3;
    float acc[4] = {0.f,0.f,0.f,0.f};
    constexpr int NW = 4*DIL + 4;
    #pragma unroll
    for (int kh = 0; kh < 5; ++kh){
        const float* rowp = &tile[(ty + kh*DIL)*S + tx4];
        float vv[NW];
        #pragma unroll
        for (int qq = 0; qq < NW/4; ++qq){
            f32x4 v = *(const f32x4*)(rowp + qq*4);
            vv[qq*4+0]=v.x; vv[qq*4+1]=v.y; vv[qq*4+2]=v.z; vv[qq*4+3]=v.w;
        }
        #pragma unroll
        for (int kw = 0; kw < 5; ++kw){
            float wk = wc[kh*5+kw];
            #pragma unroll
            for (int j = 0; j < 4; ++j)
                acc[j] += vv[kw*DIL + j] * wk;
        }
    }
    us4 o4;
    o4.x = f2bf(acc[0]); o4.y = f2bf(acc[1]); o4.z = f2bf(acc[2]); o4.w = f2bf(acc[3]);
    *(us4*)(out + (((size_t)(b*128+c))*IMG_ + y0+ty)*IMG_ + x0+tx4) = o4;
    float s = acc[0]+acc[1]+acc[2]+acc[3];
    float q = acc[0]*acc[0]+acc[1]*acc[1]+acc[2]*acc[2]+acc[3]*acc[3];
    block_red2(s, q);
    if (tid == 0){
        int bid = (b*128 + c)*64 + tileid;
        partial[bid*2] = s; partial[bid*2+1] = q;
    }
}

// ---------------- fused residual: out = mish(gn_n(xn)) + mish(gn_o(xo)); stats partial of out.
__global__ __launch_bounds__(256) void k_addmish(const ushort_t* __restrict__ xn, const float* __restrict__ stn,
                                                 const float* __restrict__ wn, const float* __restrict__ bn,
                                                 const ushort_t* __restrict__ xo, const float* __restrict__ sto,
                                                 const float* __restrict__ wo, const float* __restrict__ bo,
                                                 ushort_t* __restrict__ out, float* __restrict__ partial){
    int bid = blockIdx.x;                 // 8192 blocks * 4096 elems
    int b = bid >> 11, c = (bid >> 4) & 127;
    int bg = b*8 + (c>>4);
    float scn = stn[bg*2+1]*wn[c], sbn = bn[c] - stn[bg*2]*scn;
    float sco = sto[bg*2+1]*wo[c], sbo = bo[c] - sto[bg*2]*sco;
    size_t e0 = (size_t)bid*4096 + threadIdx.x*16;
    us8 vn0 = *(const us8*)(xn + e0), vn1 = *(const us8*)(xn + e0 + 8);
    us8 vo0 = *(const us8*)(xo + e0), vo1 = *(const us8*)(xo + e0 + 8);
    us8 r0, r1;
    float s = 0.f, q = 0.f;
    #pragma unroll
    for (int i = 0; i < 8; ++i){
        float v = mishf(bf2f(vn0[i])*scn + sbn) + mishf(bf2f(vo0[i])*sco + sbo);
        s += v; q += v*v; r0[i] = f2bf(v);
    }
    #pragma unroll
    for (int i = 0; i < 8; ++i){
        float v = mishf(bf2f(vn1[i])*scn + sbn) + mishf(bf2f(vo1[i])*sco + sbo);
        s += v; q += v*v; r1[i] = f2bf(v);
    }
    *(us8*)(out + e0) = r0;
    *(us8*)(out + e0 + 8) = r1;
    block_red2(s, q);
    if (threadIdx.x == 0){ partial[bid*2] = s; partial[bid*2+1] = q; }
}

// ---------------- head conv: 128->1, 3x3, fused gn4+mish on input; 32x32 tile per block.
__global__ __launch_bounds__(256) void k_head(const ushort_t* __restrict__ in, const float* __restrict__ st,
                                              const float* __restrict__ gw, const float* __restrict__ gb,
                                              const float* __restrict__ w, float* __restrict__ out){
    __shared__ float tile[34*34];
    int tileid = blockIdx.x, b = blockIdx.y;
    int x0 = (tileid & 7) * 32, y0 = (tileid >> 3) * 32;
    int tid = threadIdx.x;
    int tx4 = (tid & 7) * 4, ty = tid >> 3;
    float acc[4] = {0.f,0.f,0.f,0.f};
    for (int c = 0; c < 128; ++c){
        float m  = st[(b*8 + (c>>4))*2];
        float rs = st[(b*8 + (c>>4))*2 + 1];
        float sc = rs * gw[c], sb = gb[c] - m*sc;
        const ushort_t* ip = in + ((size_t)(b*128+c))*IMG_*IMG_;
        if (c) __syncthreads();
        for (int i = tid; i < 34*34; i += 256){
            int r = i / 34, cc = i - r*34;
            int gy = refl(y0 - 1 + r, IMG_);
            int gx = refl(x0 - 1 + cc, IMG_);
            float f = bf2f(ip[(size_t)gy*IMG_ + gx]) * sc + sb;
            tile[i] = mishf(f);
        }
        __syncthreads();
        const float* wc = w + c*9;
        #pragma unroll
        for (int kh = 0; kh < 3; ++kh){
            float vv[6];
            #pragma unroll
            for (int u = 0; u < 6; ++u) vv[u] = tile[(ty+kh)*34 + tx4 + u];
            #pragma unroll
            for (int kw = 0; kw < 3; ++kw){
                float wk = wc[kh*3+kw];
                #pragma unroll
                for (int j = 0; j < 4; ++j) acc[j] += vv[kw+j] * wk;
            }
        }
    }
    float4 o;
    o.x = acc[0]; o.y = acc[1]; o.z = acc[2]; o.w = acc[3];
    *(float4*)(out + ((size_t)b*IMG_ + y0+ty)*IMG_ + x0+tx4) = o;
}

// =======================================================================

struct WsMap {
    float *t, *skip, *t2, *qkvf, *ffh, *img, *ybuf, *partial, *stats;
    ushort_t *nb, *ab, *gb, *cat, *wb_qkv, *wb_out, *wb_w1, *wb_w2, *wb_pe, *wb_skip, *wb_ol, *cA, *cB;
};

static void run_block(const float* an, const ushort_t* qw, const ushort_t* ow,
                      const float* fn, const ushort_t* w1, const ushort_t* w2,
                      float* t, const WsMap& W, hipStream_t stream){
    k_rms<true><<<M_, 256, 0, stream>>>(t, an, nullptr, W.nb);
    k_gemm<<<dim3(3*D_/64, M_/64), 256, 0, stream>>>(W.nb, qw, W.qkvf, nullptr, nullptr, 3*D_, D_);
    k_attn<<<B_*NH_*L_, 256, 0, stream>>>(W.qkvf, W.ab);
    k_gemm<<<dim3(D_/64, M_/64), 256, 0, stream>>>(W.ab, ow, t, nullptr, t, D_, D_);
    k_rms<true><<<M_, 256, 0, stream>>>(t, fn, nullptr, W.nb);
    k_gemm<<<dim3(2*FF_/64, M_/64), 256, 0, stream>>>(W.nb, w1, W.ffh, nullptr, nullptr, 2*FF_, D_);
    k_glu<<<(M_*FF_)/1024, 256, 0, stream>>>(W.ffh, W.gb);
    k_gemm<<<dim3(D_/64, M_/64), 256, 0, stream>>>(W.gb, w2, t, nullptr, t, D_, FF_);
}

extern "C" void kernel_launch(void* const* d_in, const int* in_sizes, int n_in,
                              void* d_out, int out_size, void* d_ws, size_t ws_size,
                              hipStream_t stream){
    const float* x              = (const float*)d_in[0];
    const float* pe_norm_w      = (const float*)d_in[1];
    const float* pe_proj_w      = (const float*)d_in[2];
    const float* pe_proj_b      = (const float*)d_in[3];
    const float* pe_norm_out_w  = (const float*)d_in[4];
    const float* pos_embed      = (const float*)d_in[5];
    const float* in_attn_norm_w = (const float*)d_in[6];
    const float* in_qkv_w       = (const float*)d_in[7];
    const float* in_out_w       = (const float*)d_in[8];
    const float* in_ff_norm_w   = (const float*)d_in[9];
    const float* in_w1          = (const float*)d_in[10];
    const float* in_w2          = (const float*)d_in[11];
    const float* mid_attn_norm_w= (const float*)d_in[12];
    const float* mid_qkv_w      = (const float*)d_in[13];
    const float* mid_out_w      = (const float*)d_in[14];
    const float* mid_ff_norm_w  = (const float*)d_in[15];
    const float* mid_w1         = (const float*)d_in[16];
    const float* mid_w2         = (const float*)d_in[17];
    const float* out_skip_w     = (const float*)d_in[18];
    const float* out_skip_b     = (const float*)d_in[19];
    const float* out_attn_norm_w= (const float*)d_in[20];
    const float* out_qkv_w      = (const float*)d_in[21];
    const float* out_out_w      = (const float*)d_in[22];
    const float* out_ff_norm_w  = (const float*)d_in[23];
    const float* out_w1         = (const float*)d_in[24];
    const float* out_w2         = (const float*)d_in[25];
    const float* final_norm_w   = (const float*)d_in[26];
    const float* ol_proj_w      = (const float*)d_in[27];
    const float* ol_proj_b      = (const float*)d_in[28];
    const float* rb_conv_in_w   = (const float*)d_in[29];
    const float* rb_gn_w        = (const float*)d_in[30];
    const float* rb_gn_b        = (const float*)d_in[31];
    const float* rb_conv1_w     = (const float*)d_in[32];
    const float* rb_conv2_w     = (const float*)d_in[33];
    const float* head_conv_w    = (const float*)d_in[34];

    WsMap W;
    float* f = (float*)d_ws;
    const size_t TD = (size_t)M_*D_;
    W.t      = f;                       // 786432
    W.skip   = f + TD;
    W.t2     = f + 2*TD;
    W.qkvf   = f + 3*TD;                // 2359296
    W.ffh    = f + 3*TD + (size_t)M_*3*D_;   // 6291456
    W.img    = W.ffh + (size_t)M_*2*FF_;     // 786432
    W.ybuf   = W.img + TD;
    W.partial= W.ybuf + TD;             // 262144
    W.stats  = W.partial + 262144;      // 5*64 = 320 -> pad
    ushort_t* u = (ushort_t*)(W.stats + 448);   // keeps 16B alignment
    W.nb   = u;                  u += TD;
    W.ab   = u;                  u += TD;
    W.gb   = u;                  u += (size_t)M_*FF_;
    W.cat  = u;                  u += (size_t)M_*2*D_;
    W.wb_qkv = u;                u += (size_t)10*D_*3*D_;
    W.wb_out = u;                u += (size_t)10*D_*D_;
    W.wb_w1  = u;                u += (size_t)10*D_*2*FF_;
    W.wb_w2  = u;                u += (size_t)10*FF_*D_;
    W.wb_pe  = u;                u += (size_t)D_*D_;
    W.wb_skip= u;                u += (size_t)2*D_*D_;
    W.wb_ol  = u;                u += (size_t)D_*D_;
    W.cA   = u;                  u += (size_t)NCONV_;
    W.cB   = u;

    float* st0 = W.stats;       float* st1 = W.stats + 64;
    float* st2 = W.stats + 128; float* st3 = W.stats + 192;
    float* st4 = W.stats + 256;

    // --- weight convert+transpose (bf16, [N][K])
    k_wt<<<dim3(3*D_/32, D_/32, 10), 256, 0, stream>>>(in_qkv_w, mid_qkv_w, out_qkv_w, 6, 3, W.wb_qkv, D_, 3*D_);
    k_wt<<<dim3(D_/32, D_/32, 10), 256, 0, stream>>>(in_out_w, mid_out_w, out_out_w, 6, 3, W.wb_out, D_, D_);
    k_wt<<<dim3(2*FF_/32, D_/32, 10), 256, 0, stream>>>(in_w1, mid_w1, out_w1, 6, 3, W.wb_w1, D_, 2*FF_);
    k_wt<<<dim3(D_/32, FF_/32, 10), 256, 0, stream>>>(in_w2, mid_w2, out_w2, 6, 3, W.wb_w2, FF_, D_);
    k_wt<<<dim3(D_/32, D_/32, 1), 256, 0, stream>>>(pe_proj_w, nullptr, nullptr, 1, 0, W.wb_pe, D_, D_);
    k_wt<<<dim3(D_/32, 2*D_/32, 1), 256, 0, stream>>>(out_skip_w, nullptr, nullptr, 1, 0, W.wb_skip, 2*D_, D_);
    k_wt<<<dim3(D_/32, D_/32, 1), 256, 0, stream>>>(ol_proj_w, nullptr, nullptr, 1, 0, W.wb_ol, D_, D_);

    // --- patch embed
    k_patchify<<<(B_*L_*PD_)/256, 256, 0, stream>>>(x, W.t2);
    k_rms<true><<<M_, 256, 0, stream>>>(W.t2, pe_norm_w, nullptr, W.nb);
    k_gemm<<<dim3(D_/64, M_/64), 256, 0, stream>>>(W.nb, W.wb_pe, W.t2, pe_proj_b, nullptr, D_, D_);
    k_rms<false><<<M_, 256, 0, stream>>>(W.t2, pe_norm_out_w, pos_embed, W.t);

    // --- 6 in blocks
    for (int i = 0; i < 6; ++i){
        run_block(in_attn_norm_w + (size_t)i*D_, W.wb_qkv + (size_t)i*D_*3*D_,
                  W.wb_out + (size_t)i*D_*D_, in_ff_norm_w + (size_t)i*D_,
                  W.wb_w1 + (size_t)i*D_*2*FF_, W.wb_w2 + (size_t)i*FF_*D_,
                  W.t, W, stream);
    }
    hipMemcpyAsync(W.skip, W.t, TD*sizeof(float), hipMemcpyDeviceToDevice, stream);

    // --- 3 middle blocks
    for (int i = 0; i < 3; ++i){
        int z = 6 + i;
        run_block(mid_attn_norm_w + (size_t)i*D_, W.wb_qkv + (size_t)z*D_*3*D_,
                  W.wb_out + (size_t)z*D_*D_, mid_ff_norm_w + (size_t)i*D_,
                  W.wb_w1 + (size_t)z*D_*2*FF_, W.wb_w2 + (size_t)z*FF_*D_,
                  W.t, W, stream);
    }

    // --- skip concat projection
    k_cat<<<(M_*D_)/1024, 256, 0, stream>>>(W.t, W.skip, W.cat);
    k_gemm<<<dim3(D_/64, M_/64), 256, 0, stream>>>(W.cat, W.wb_skip, W.t2, out_skip_b, nullptr, D_, 2*D_);

    // --- out block
    run_block(out_attn_norm_w, W.wb_qkv + (size_t)9*D_*3*D_, W.wb_out + (size_t)9*D_*D_,
              out_ff_norm_w, W.wb_w1 + (size_t)9*D_*2*FF_, W.wb_w2 + (size_t)9*FF_*D_,
              W.t2, W, stream);

    // --- final norm + out proj + unpatchify
    k_rms<true><<<M_, 256, 0, stream>>>(W.t2, final_norm_w, nullptr, W.nb);
    k_gemm<<<dim3(PD_/64, M_/64), 256, 0, stream>>>(W.nb, W.wb_ol, W.ybuf, ol_proj_b, nullptr, PD_, D_);
    k_unpatchify<<<(B_*3*IMG_*IMG_)/256, 256, 0, stream>>>(W.ybuf, W.img);

    // --- ResNet head (fused gn+mish pipeline, bf16 buffers)
    k_conv_in<<<dim3(256, 128, 4), 256, 0, stream>>>(W.img, rb_conv_in_w, W.cA, W.partial);
    k_gn_fin<<<32, 256, 0, stream>>>(W.partial, 4096, st0);
    k_dw<2,1><<<dim3(64, 128, 4), 256, 0, stream>>>(W.cA, st0, rb_gn_w, rb_gn_b, rb_conv1_w, W.cB, W.partial);
    k_gn_fin<<<32, 256, 0, stream>>>(W.partial, 1024, st1);
    k_addmish<<<8192, 256, 0, stream>>>(W.cB, st1, rb_gn_w+128, rb_gn_b+128,
                                        W.cA, st0, rb_gn_w, rb_gn_b, W.cA, W.partial);
    k_gn_fin<<<32, 256, 0, stream>>>(W.partial, 256, st2);
    k_dw<6,3><<<dim3(64, 128, 4), 256, 0, stream>>>(W.cA, st2, rb_gn_w+256, rb_gn_b+256, rb_conv2_w, W.cB, W.partial);
    k_gn_fin<<<32, 256, 0, stream>>>(W.partial, 1024, st3);
    k_addmish<<<8192, 256, 0, stream>>>(W.cB, st3, rb_gn_w+384, rb_gn_b+384,
                                        W.cA, st2, rb_gn_w+256, rb_gn_b+256, W.cA, W.partial);
    k_gn_fin<<<32, 256, 0, stream>>>(W.partial, 256, st4);
    k_head<<<dim3(64, 4), 256, 0, stream>>>(W.cA, st4, rb_gn_w+512, rb_gn_b+512, head_conv_w, (float*)d_out);
}